// Round 5
// baseline (261.548 us; speedup 1.0000x reference)
//
#include <hip/hip_runtime.h>
#include <math.h>

#define NAG 10
#define PP  65536
#define EE  64
#define INW 16
#define TP  4              // p's per group (one wave each)
#define RR  (TP*NAG)       // 40 rows
#define SH  72             // bf16 LDS stride for row-major 64-wide tiles (144 B, 16B-aligned rows)
#define SX  40             // bf16 LDS stride for X tile (80 B rows, 16B-aligned)
#define SVT 52             // rows-stride for col-major V^T (104 B per col, 8B-aligned)
#define SU  68             // f32 stride for u output tile
#define NBLK 1280
#define NGRP (PP/TP)       // 16384

typedef __attribute__((ext_vector_type(8))) short short8;
typedef __attribute__((ext_vector_type(4))) short short4v;
typedef __attribute__((ext_vector_type(4))) float f32x4;

#if defined(__has_builtin)
#if __has_builtin(__builtin_amdgcn_mfma_f32_16x16x16bf16_1k)
#define HAVE_MFMA16 1
#endif
#endif

__device__ __forceinline__ short f2bf(float x){
    unsigned u = __float_as_uint(x);
    return (short)((u + 0x8000u) >> 16);     // round-nearest (ties away)
}
__device__ __forceinline__ float bf2f(short s){
    return __uint_as_float(((unsigned)(unsigned short)s) << 16);
}
__device__ __forceinline__ unsigned pack2(float a, float b){
    return (unsigned)(unsigned short)f2bf(a) | ((unsigned)(unsigned short)f2bf(b) << 16);
}

__global__ __launch_bounds__(256, 5) void mpnn_mfma4(
    const float* __restrict__ inp,
    const float* __restrict__ W_enc, const float* __restrict__ b_enc,
    const float* __restrict__ W_goal, const float* __restrict__ b_goal,
    const float* __restrict__ Wq, const float* __restrict__ Wk,
    const float* __restrict__ Wv, const float* __restrict__ Wo,
    const float* __restrict__ W_upd, const float* __restrict__ b_upd,
    float* __restrict__ out)
{
    // pool: [hs 6912][qsb 6912][ksb 6912][vsbT 6656] = 27392 B
    //  - init overlay:  Wc (64x64 f32 = 16384 B) at pool base
    //  - epilog overlay: outt_u (40*SU*4 = 10880 B) + outt_h (8*64*4 = 2048 B) at ksb base
    __shared__ __align__(16) char pool[27392];
    __shared__ __align__(16) short Xs[48 * SX];
    __shared__ float goal_s[TP][2];
#ifndef HAVE_MFMA16
    __shared__ float attn_s[TP][NAG][12];
#endif

    short* const hs   = (short*)pool;
    short* const qsb  = hs  + 48*SH;
    short* const ksb  = qsb + 48*SH;
    short* const vsbT = ksb + 48*SH;
    float* const Wc     = (float*)pool;
    float* const outt_u = (float*)(pool + 2*2*48*SH);          // at ksb
    float* const outt_h = (float*)(pool + 2*2*48*SH) + RR*SU;  // after outt_u

    const int tid  = threadIdx.x;
    const int w    = tid >> 6;      // wave id == col-tile == p_local for attention
    const int l    = tid & 63;
    const int lrow = l & 15;
    const int lk   = l >> 4;
    const int col  = 16*w + lrow;

    // ---- zero X once (cols 16..31 and rows 40..47 stay zero forever)
    for (int i = tid; i < 48*SX; i += 256) Xs[i] = 0;

    // ---- Wc = Wo @ W_upd[64:128]  (once per block, fp32 in LDS)
    for (int i = tid; i < EE*EE; i += 256) {
        const int k = i >> 6, n = i & 63;
        float s = 0.f;
        #pragma unroll 8
        for (int d = 0; d < EE; ++d)
            s = fmaf(Wo[k*EE + d], W_upd[(EE + d)*EE + n], s);
        Wc[i] = s;
    }
    __syncthreads();

    // ---- B-fragment preload (all weights live in registers)
    short8 fenc, fqw[2], fkw[2], fvw[2], fuw[2], fcw[2];
    #pragma unroll
    for (int j = 0; j < 8; ++j) {
        int k = lk*8 + j;
        fenc[j] = (k < 14) ? f2bf(W_enc[k*EE + col]) : (short)0;
    }
    #pragma unroll
    for (int ks = 0; ks < 2; ++ks) {
        #pragma unroll
        for (int j = 0; j < 8; ++j) {
            int k = 32*ks + lk*8 + j;
            fqw[ks][j] = f2bf(Wq[k*EE + col]);
            fkw[ks][j] = f2bf(Wk[k*EE + col]);
            fvw[ks][j] = f2bf(Wv[k*EE + col]);
            fuw[ks][j] = f2bf(W_upd[k*EE + col]);
            fcw[ks][j] = f2bf(Wc[k*EE + col]);
        }
    }
    const float bencv = b_enc[col];
    const float bupdv = b_upd[col];
    const float wg0 = W_goal[l], wg1 = W_goal[EE + l], bg = b_goal[l];

    // ---- input staging lanes: lane -> one float4 (row r_=pl*NAG+a, quarter q_)
    const bool hasx = tid < RR*4;
    const int  r_ = tid >> 2, q_ = tid & 3;
    const int  pl_ = r_ / NAG, a_ = r_ - pl_*NAG;
    const size_t xbase = (size_t)a_*PP*INW + (size_t)pl_*INW + (size_t)q_*4;
    f32x4 xin = {0.f,0.f,0.f,0.f};
    if (hasx) xin = __builtin_nontemporal_load(
        (const f32x4*)(inp + xbase + (size_t)blockIdx.x * (TP*INW)));

    // ---- prologue stage of group g0 = blockIdx.x
    if (hasx) {
        uint2 pk = { pack2(xin[0], xin[1]), pack2(xin[2], xin[3]) };
        *(uint2*)&Xs[r_*SX + q_*4] = pk;   // goal vals land in X cols 14,15: fenc is 0 there
        if (q_ == 3 && a_ == 0) { goal_s[pl_][0] = xin[2]; goal_s[pl_][1] = xin[3]; }
        if ((int)blockIdx.x + NBLK < NGRP)
            xin = __builtin_nontemporal_load(
                (const f32x4*)(inp + xbase + (size_t)(blockIdx.x + NBLK) * (TP*INW)));
    }
    __syncthreads();   // orders: Wc reads, stage writes, Xs zeros vs loop body

    for (int g = blockIdx.x; g < NGRP; g += NBLK) {
        const int p0 = g * TP;

        // leader h2 (reads goal_s staged for g; before this iter's stage overwrites it)
        const float h2l = fmaxf(fmaf(goal_s[w][0], wg0,
                           fmaf(goal_s[w][1], wg1, bg)), 0.f);

        // ---- encoder: h = relu(X @ W_enc + b_enc)
        #pragma unroll
        for (int rt = 0; rt < 3; ++rt) {
            const short8 ax = *reinterpret_cast<const short8*>(&Xs[(16*rt + lrow)*SX + lk*8]);
            f32x4 acc = {0.f,0.f,0.f,0.f};
            acc = __builtin_amdgcn_mfma_f32_16x16x32_bf16(ax, fenc, acc, 0,0,0);
            #pragma unroll
            for (int j = 0; j < 4; ++j)
                hs[(16*rt + lk*4 + j)*SH + col] = f2bf(fmaxf(acc[j] + bencv, 0.f));
        }
        __syncthreads();   // C

        // ---- Q,K row-major; V col-major (vsbT) for the m-MFMA B-frags
        #pragma unroll
        for (int rt = 0; rt < 3; ++rt) {
            const short8 a0 = *reinterpret_cast<const short8*>(&hs[(16*rt + lrow)*SH + lk*8]);
            const short8 a1 = *reinterpret_cast<const short8*>(&hs[(16*rt + lrow)*SH + 32 + lk*8]);
            f32x4 qa = {0.f,0.f,0.f,0.f}, ka = {0.f,0.f,0.f,0.f}, va = {0.f,0.f,0.f,0.f};
            qa = __builtin_amdgcn_mfma_f32_16x16x32_bf16(a0, fqw[0], qa, 0,0,0);
            qa = __builtin_amdgcn_mfma_f32_16x16x32_bf16(a1, fqw[1], qa, 0,0,0);
            ka = __builtin_amdgcn_mfma_f32_16x16x32_bf16(a0, fkw[0], ka, 0,0,0);
            ka = __builtin_amdgcn_mfma_f32_16x16x32_bf16(a1, fkw[1], ka, 0,0,0);
            va = __builtin_amdgcn_mfma_f32_16x16x32_bf16(a0, fvw[0], va, 0,0,0);
            va = __builtin_amdgcn_mfma_f32_16x16x32_bf16(a1, fvw[1], va, 0,0,0);
            #pragma unroll
            for (int j = 0; j < 4; ++j) {
                const int ro = (16*rt + lk*4 + j)*SH + col;
                qsb[ro] = f2bf(qa[j]);
                ksb[ro] = f2bf(ka[j]);
            }
            uint2 vpk = { pack2(va[0], va[1]), pack2(va[2], va[3]) };
            *(uint2*)&vsbT[col*SVT + 16*rt + lk*4] = vpk;   // rows consecutive -> b64
        }
        const float h0 = bf2f(hs[(w*NAG)*SH + l]);   // agent-0 h, elem l, p=p0+w
        __syncthreads();   // D

        // ---- attention for p = w, fully in-register softmax
        {
            const int r0 = w * NAG;
            // S^T = K @ Q^T: B-frag of Q^T == A-frag addressing of Q
            const short8 aK0 = *reinterpret_cast<const short8*>(&ksb[(r0+lrow)*SH + lk*8]);
            const short8 aK1 = *reinterpret_cast<const short8*>(&ksb[(r0+lrow)*SH + 32 + lk*8]);
            const short8 aQ0 = *reinterpret_cast<const short8*>(&qsb[(r0+lrow)*SH + lk*8]);
            const short8 aQ1 = *reinterpret_cast<const short8*>(&qsb[(r0+lrow)*SH + 32 + lk*8]);
            f32x4 st = {0.f,0.f,0.f,0.f};
            st = __builtin_amdgcn_mfma_f32_16x16x32_bf16(aK0, aQ0, st, 0,0,0);
            st = __builtin_amdgcn_mfma_f32_16x16x32_bf16(aK1, aQ1, st, 0,0,0);
            // lane holds S[q=lrow][k=lk*4+j]
            const int q = lrow;
            float c[4]; float mx4 = -1e30f;
            #pragma unroll
            for (int j = 0; j < 4; ++j) {
                const int k = lk*4 + j;
                const bool valid = (q < NAG) && (k < NAG) && (k != q) && (k != 0);
                c[j] = valid ? st[j] * 0.125f : -1e30f;
                mx4 = fmaxf(mx4, c[j]);
            }
            float mx = fmaxf(mx4, __shfl_xor(mx4, 16, 64));
            mx = fmaxf(mx, __shfl_xor(mx, 32, 64));
            float e[4], s4 = 0.f;
            #pragma unroll
            for (int j = 0; j < 4; ++j) { e[j] = __expf(c[j] - mx); s4 += e[j]; }
            float s = s4;
            s += __shfl_xor(s, 16, 64);
            s += __shfl_xor(s, 32, 64);
            const float inv = 1.f / s;

#ifdef HAVE_MFMA16
            // P A-frag for 16x16x16 == S^T D-frag layout (q=l&15, k=(l>>4)*4+j)
            short4v pa;
            #pragma unroll
            for (int j = 0; j < 4; ++j) pa[j] = f2bf(e[j] * inv);
            #pragma unroll
            for (int t = 0; t < 4; ++t) {
                // B-frag: V[k=lk*4+j][e=16t+lrow] from col-major vsbT (2 aligned b32)
                const short* vp = &vsbT[(16*t + lrow)*SVT + r0 + lk*4];
                const unsigned lo = *(const unsigned*)(vp);
                const unsigned hi = *(const unsigned*)(vp + 2);
                short4v vb;
                vb[0] = (short)(lo & 0xffff); vb[1] = (short)(lo >> 16);
                vb[2] = (short)(hi & 0xffff); vb[3] = (short)(hi >> 16);
                f32x4 md = {0.f,0.f,0.f,0.f};
                md = __builtin_amdgcn_mfma_f32_16x16x16bf16_1k(pa, vb, md, 0,0,0);
                // D: lane holds m[a=lk*4+j][e=16t+lrow]
                #pragma unroll
                for (int j = 0; j < 4; ++j) {
                    const int a = lk*4 + j;
                    if (a < NAG) qsb[(r0+a)*SH + 16*t + lrow] = f2bf(md[j]);
                }
            }
#else
            if (q < NAG) {
                #pragma unroll
                for (int j = 0; j < 4; ++j) {
                    const int k = lk*4 + j;
                    if (k < NAG) attn_s[w][q][k] = e[j] * inv;
                }
            }
            float vv[NAG];
            #pragma unroll
            for (int kk = 0; kk < NAG; ++kk) vv[kk] = bf2f(vsbT[l*SVT + r0 + kk]);
            #pragma unroll
            for (int a = 0; a < NAG; ++a) {
                float m = 0.f;
                #pragma unroll
                for (int kk = 0; kk < NAG; ++kk)
                    m = fmaf(attn_s[w][a][kk], vv[kk], m);
                qsb[(r0+a)*SH + l] = f2bf(m);
            }
#endif
        }
        // ---- stage NEXT group's X/goal (barrier D ordered this vs enc reads)
        if (hasx && g + NBLK < NGRP) {
            uint2 pk = { pack2(xin[0], xin[1]), pack2(xin[2], xin[3]) };
            *(uint2*)&Xs[r_*SX + q_*4] = pk;
            if (q_ == 3 && a_ == 0) { goal_s[pl_][0] = xin[2]; goal_s[pl_][1] = xin[3]; }
            if (g + 2*NBLK < NGRP)
                xin = __builtin_nontemporal_load(
                    (const f32x4*)(inp + xbase + (size_t)(g + 2*NBLK) * (TP*INW)));
        }
        __syncthreads();   // G

        // ---- u = relu(h @ Wu_top + m @ Wc + b_upd); build output tile over dead ksb/vsbT
        #pragma unroll
        for (int rt = 0; rt < 3; ++rt) {
            const short8 a0 = *reinterpret_cast<const short8*>(&hs [(16*rt + lrow)*SH + lk*8]);
            const short8 a1 = *reinterpret_cast<const short8*>(&hs [(16*rt + lrow)*SH + 32 + lk*8]);
            const short8 a2 = *reinterpret_cast<const short8*>(&qsb[(16*rt + lrow)*SH + lk*8]);
            const short8 a3 = *reinterpret_cast<const short8*>(&qsb[(16*rt + lrow)*SH + 32 + lk*8]);
            f32x4 ua = {0.f,0.f,0.f,0.f};
            ua = __builtin_amdgcn_mfma_f32_16x16x32_bf16(a0, fuw[0], ua, 0,0,0);
            ua = __builtin_amdgcn_mfma_f32_16x16x32_bf16(a1, fuw[1], ua, 0,0,0);
            ua = __builtin_amdgcn_mfma_f32_16x16x32_bf16(a2, fcw[0], ua, 0,0,0);
            ua = __builtin_amdgcn_mfma_f32_16x16x32_bf16(a3, fcw[1], ua, 0,0,0);
            #pragma unroll
            for (int j = 0; j < 4; ++j) {
                const int r = 16*rt + lk*4 + j;
                if (r < RR) outt_u[r*SU + col] = fmaxf(ua[j] + bupdv, 0.f);
            }
        }
        outt_h[(w*2 + 0)*64 + l] = h2l;
        outt_h[(w*2 + 1)*64 + l] = h0;
        __syncthreads();   // I

        // ---- coalesced full-line nontemporal stores: 1024 B / wave-instr
        float* __restrict__ outF = out + (size_t)PP*128;
        #pragma unroll
        for (int it = 0; it < 5; ++it) {
            const int flat   = it*256 + tid;
            const int a      = flat >> 7;
            const int within = flat & 127;
            const int pl     = within >> 5;
            const int j4     = within & 31;
            const float* src = (j4 < 16)
                ? &outt_u[(pl*NAG + a)*SU + j4*4]
                : &outt_h[(pl*2 + (a == 0 ? 0 : 1))*64 + (j4 - 16)*4];
            const f32x4 v = *reinterpret_cast<const f32x4*>(src);
            float* dst = (a == 0)
                ? (out  + ((size_t)(p0 + pl))*128 + j4*4)
                : (outF + ((size_t)(a-1)*PP + (size_t)(p0 + pl))*128 + j4*4);
            __builtin_nontemporal_store(v, (f32x4*)dst);
        }
    }
}

extern "C" void kernel_launch(void* const* d_in, const int* in_sizes, int n_in,
                              void* d_out, int out_size, void* d_ws, size_t ws_size,
                              hipStream_t stream) {
    const float* inp    = (const float*)d_in[0];
    const float* W_enc  = (const float*)d_in[1];
    const float* b_enc  = (const float*)d_in[2];
    const float* W_goal = (const float*)d_in[3];
    const float* b_goal = (const float*)d_in[4];
    const float* Wq     = (const float*)d_in[5];
    const float* Wk     = (const float*)d_in[6];
    const float* Wv     = (const float*)d_in[7];
    const float* Wo     = (const float*)d_in[8];
    const float* W_upd  = (const float*)d_in[9];
    const float* b_upd  = (const float*)d_in[10];

    hipLaunchKernelGGL(mpnn_mfma4, dim3(NBLK), dim3(256), 0, stream,
                       inp, W_enc, b_enc, W_goal, b_goal,
                       Wq, Wk, Wv, Wo, W_upd, b_upd, (float*)d_out);
}